// Round 7
// baseline (326.830 us; speedup 1.0000x reference)
//
#include <hip/hip_runtime.h>
#include <hip/hip_cooperative_groups.h>

namespace cg = cooperative_groups;

// FlowLenia step, SX=SY=256, C=3, K=15 — ONE cooperative kernel, 4 phases
// separated by grid.sync(). Grid 512x256 (2 blocks/CU — co-residency has
// wide margin: LDS 2x26KB of 160KB, VGPR cap 256).
//   A: blocks 0..191 row-FFT of A -> RF ; blocks 192..447 de-interleave P/A
//   B: 960 tasks (k, 4-col tile), stride-512 loop: fwd col FFT + fK mul +
//      inv col FFT -> T2
//   C: 3840 wave-tasks (k,x), stride-512 block loop: inv row FFT + growth*P
//      -> G[k][XY]
//   D: blocks 0..255 = 8x32 tiles (round-5-validated path): U=sum_j G ->
//      Sobel flow -> 5x5 reintegration -> d_out (newA | newP)

#define XY  65536
#define NC  3
#define NK  15
#define WPAD 260   // per-wave LDS FFT buffer stride (float2)

__device__ __forceinline__ float2 cmul(float2 a, float2 b) {
  return make_float2(a.x * b.x - a.y * b.y, a.x * b.y + a.y * b.x);
}

// 256-pt Stockham radix-4 FFT on a wave-private 256-float2 LDS buffer pair.
// t = lane (0..63). sign = -1 fwd, +1 inv (unnormalized). Result lands in b0.
// All waves of the block must call together (uniform control flow per block).
__device__ __forceinline__ void fft256_lds(float2* b0, float2* b1, int t, float sign) {
  float2* src = b0;
  float2* dst = b1;
#pragma unroll
  for (int stage = 0; stage < 4; ++stage) {
    __syncthreads();  // covers caller's fill and previous stage's writes
    const int Ns = 1 << (2 * stage);
    float2 v0 = src[t];
    float2 v1 = src[t + 64];
    float2 v2 = src[t + 128];
    float2 v3 = src[t + 192];
    const int jm = t & (Ns - 1);
    float ang = sign * 6.283185307179586f * (float)jm / (float)(Ns * 4);
    float sn, cs;
    __sincosf(ang, &sn, &cs);
    float2 w1 = make_float2(cs, sn);
    float2 w2 = cmul(w1, w1);
    float2 w3 = cmul(w2, w1);
    v1 = cmul(v1, w1);
    v2 = cmul(v2, w2);
    v3 = cmul(v3, w3);
    float2 a0 = make_float2(v0.x + v2.x, v0.y + v2.y);
    float2 a1 = make_float2(v0.x - v2.x, v0.y - v2.y);
    float2 a2 = make_float2(v1.x + v3.x, v1.y + v3.y);
    float2 a3 = make_float2(v1.x - v3.x, v1.y - v3.y);
    float2 ia3 = make_float2(-sign * a3.y, sign * a3.x);  // (sign*i)*a3
    const int idxD = ((t >> (2 * stage)) << (2 * stage)) * 4 + jm;  // (t/Ns)*4Ns+jm
    dst[idxD]          = make_float2(a0.x + a2.x, a0.y + a2.y);
    dst[idxD + Ns]     = make_float2(a1.x + ia3.x, a1.y + ia3.y);
    dst[idxD + 2 * Ns] = make_float2(a0.x - a2.x, a0.y - a2.y);
    dst[idxD + 3 * Ns] = make_float2(a1.x - ia3.x, a1.y - ia3.y);
    float2* tmp = src; src = dst; dst = tmp;
  }
  __syncthreads();
}

// Phase-D tile geometry (validated in round 5's k_flow_reint).
#define UROW 14
#define UCOLW 38
#define FROW 12
#define FCOLW 36
#define LPAD 40

__global__ __launch_bounds__(256, 2) void k_fused(
    const float* __restrict__ A, const float* __restrict__ P,
    const float* __restrict__ fKr, const float* __restrict__ fKi,
    const float* __restrict__ m, const float* __restrict__ s,
    float2* __restrict__ RF, float2* __restrict__ T2,
    float* __restrict__ G, float* __restrict__ Aplan,
    float* __restrict__ Asum, float* __restrict__ Pplan,
    float* __restrict__ outA, float* __restrict__ outP) {
  cg::grid_group grid = cg::this_grid();
  // Union: FFT phases need 8*WPAD=2080 float2; phase D needs 6560 floats.
  __shared__ float2 smem2[3280];
  float2* fbuf = smem2;
  float* smem = (float*)smem2;
  const int tid = threadIdx.x;
  const int bid = blockIdx.x;
  const int w = tid >> 6, lane = tid & 63;

  // ---------------- Phase A: row FFT (0..191) | prep (192..447) ----------
  if (bid < 192) {
    const int g = bid * 4 + w;        // 768 tasks (c,x)
    const int c = g >> 8, x = g & 255;
    float2* b0 = fbuf + w * WPAD;
    float2* b1 = fbuf + (4 + w) * WPAD;
#pragma unroll
    for (int r = 0; r < 4; ++r) {
      int y = lane + 64 * r;
      b0[y] = make_float2(A[(x * 256 + y) * NC + c], 0.0f);
    }
    fft256_lds(b0, b1, lane, -1.0f);
#pragma unroll
    for (int r = 0; r < 4; ++r) {
      int y = lane + 64 * r;
      RF[(c * 256 + x) * 256 + y] = b0[y];
    }
  } else if (bid < 448) {
    const int b = (bid - 192) * 256 + tid;   // 65536 cells
    float a0 = A[b * 3 + 0], a1 = A[b * 3 + 1], a2 = A[b * 3 + 2];
    Aplan[0 * XY + b] = a0;
    Aplan[1 * XY + b] = a1;
    Aplan[2 * XY + b] = a2;
    Asum[b] = a0 + a1 + a2;
#pragma unroll
    for (int k = 0; k < NK; ++k) Pplan[k * XY + b] = P[b * NK + k];
  }
  grid.sync();

  // ---------------- Phase B: col FFT + fK mul + inv col FFT --------------
  for (int tb = bid; tb < 960; tb += 512) {
    const int k = tb >> 6;            // 15 kernels
    const int y0 = (tb & 63) << 2;    // 64 tiles of 4 columns
    const int c = k % 3;
    // Tile load: thread tid = row x; chunk r holds cols y0+2r, y0+2r+1.
#pragma unroll
    for (int r = 0; r < 2; ++r) {
      const float4* srcp = (const float4*)(RF + (c * XY + tid * 256 + y0));
      float4 v = srcp[r];
      fbuf[(2 * r) * WPAD + tid]     = make_float2(v.x, v.y);
      fbuf[(2 * r + 1) * WPAD + tid] = make_float2(v.z, v.w);
    }
    float2* b0 = fbuf + w * WPAD;     // wave w owns column y0+w
    float2* b1 = fbuf + (4 + w) * WPAD;
    fft256_lds(b0, b1, lane, -1.0f);  // leading barrier covers tile fill
    const int y = y0 + w;
    float2 fa[4];
#pragma unroll
    for (int r = 0; r < 4; ++r) fa[r] = b0[lane + 64 * r];
#pragma unroll
    for (int r = 0; r < 4; ++r) {
      const int x = lane + 64 * r;
      const int fi = (x * 256 + y) * NK + k;
      float2 Kv = make_float2(fKr[fi], fKi[fi]);
      b0[x] = cmul(Kv, fa[r]);
    }
    fft256_lds(b0, b1, lane, 1.0f);   // trailing barrier: tile block-visible
#pragma unroll
    for (int r = 0; r < 2; ++r) {
      float2 v0 = fbuf[(2 * r) * WPAD + tid];
      float2 v1 = fbuf[(2 * r + 1) * WPAD + tid];
      ((float4*)(T2 + (k * XY + tid * 256 + y0)))[r] =
          make_float4(v0.x, v0.y, v1.x, v1.y);
    }
    __syncthreads();                  // protect fbuf before next loop pass
  }
  grid.sync();

  // ---------------- Phase C: inv row FFT + growth*P -> G -----------------
  for (int tb = bid; tb < 960; tb += 512) {
    const int g = tb * 4 + w;         // 3840 tasks (k,x)
    const int k = g >> 8, x = g & 255;
    float2* b0 = fbuf + w * WPAD;
    float2* b1 = fbuf + (4 + w) * WPAD;
    const float2* srcp = T2 + (k * XY + x * 256);
#pragma unroll
    for (int r = 0; r < 4; ++r) {
      int y = lane + 64 * r;
      b0[y] = srcp[y];
    }
    fft256_lds(b0, b1, lane, 1.0f);
    const float mk = m[k];
    const float sk = s[k];
    const float inv2s2 = 0.5f / (sk * sk);
    const float* pk = Pplan + k * XY + x * 256;
    float* gk = G + k * XY + x * 256;
#pragma unroll
    for (int r = 0; r < 4; ++r) {
      int y = lane + 64 * r;
      float U = b0[y].x * (1.0f / 65536.0f);
      float d = U - mk;
      float gr = 2.0f * __expf(-d * d * inv2s2) - 1.0f;
      gk[y] = gr * pk[y];
    }
    __syncthreads();                  // protect fbuf before next loop pass
  }
  grid.sync();

  // ---------------- Phase D: flow + reintegration (blocks 0..255) --------
  // Round-5-validated structure: 8x32 tile, one cell per thread, 25 shifts.
  if (bid < 256) {
    float* Uc = smem;                         // [3][14][40]
    float* As = Uc + 3 * UROW * LPAD;         // [14][40]
    float* Ft = As + UROW * LPAD;             // [6][12][40]
    float* At = Ft + 6 * FROW * LPAD;         // [3][12][40]
    float* PoutS = smem;                      // staging aliases (post-barrier)
    float* AoutS = smem + 8 * 480;

    const int x0 = (bid >> 3) << 3;           // 32 x-tiles of 8 rows
    const int y0 = (bid & 7) << 5;            // 8 y-tiles of 32 cols

    // D1: load U (=sum of 5 G planes per channel) + Asum, halo 3, wrapped.
    for (int i = tid; i < UROW * UCOLW; i += 256) {
      const int lx = i / UCOLW, ly = i - lx * UCOLW;
      const int gx = (x0 - 3 + lx) & 255;
      const int gy = (y0 - 3 + ly) & 255;
      const int gb = gx * 256 + gy;
      As[lx * LPAD + ly] = Asum[gb];
#pragma unroll
      for (int c = 0; c < NC; ++c) {
        float su = 0.f;
#pragma unroll
        for (int j = 0; j < 5; ++j) su += G[(c + 3 * j) * XY + gb];
        Uc[c * UROW * LPAD + lx * LPAD + ly] = su;
      }
    }
    __syncthreads();

    // D2: compute F (6 planes) + stage A (3 planes), halo 2.
    const float MA = 4.35f;
    for (int i = tid; i < FROW * FCOLW; i += 256) {
      const int j = i / FCOLW, l = i - j * FCOLW;
      const int wx = (x0 - 2 + j) & 255;
      const int wy = (y0 - 2 + l) & 255;
      const bool xm = (wx != 0), xp = (wx != 255);
      const bool ym = (wy != 0), yp = (wy != 255);
      float a00 = (xm && ym) ? As[(j) * LPAD + l] : 0.f;
      float a01 = xm ? As[(j) * LPAD + l + 1] : 0.f;
      float a02 = (xm && yp) ? As[(j) * LPAD + l + 2] : 0.f;
      float a10 = ym ? As[(j + 1) * LPAD + l] : 0.f;
      float a12 = yp ? As[(j + 1) * LPAD + l + 2] : 0.f;
      float a20 = (xp && ym) ? As[(j + 2) * LPAD + l] : 0.f;
      float a21 = xp ? As[(j + 2) * LPAD + l + 1] : 0.f;
      float a22 = (xp && yp) ? As[(j + 2) * LPAD + l + 2] : 0.f;
      float cg0 = (a20 + 2.f * a21 + a22) - (a00 + 2.f * a01 + a02);
      float cg1 = (a02 + 2.f * a12 + a22) - (a00 + 2.f * a10 + a20);
      const int wb = wx * 256 + wy;
#pragma unroll
      for (int c = 0; c < NC; ++c) {
        const float* up = Uc + c * UROW * LPAD;
        float u00 = (xm && ym) ? up[(j) * LPAD + l] : 0.f;
        float u01 = xm ? up[(j) * LPAD + l + 1] : 0.f;
        float u02 = (xm && yp) ? up[(j) * LPAD + l + 2] : 0.f;
        float u10 = ym ? up[(j + 1) * LPAD + l] : 0.f;
        float u12 = yp ? up[(j + 1) * LPAD + l + 2] : 0.f;
        float u20 = (xp && ym) ? up[(j + 2) * LPAD + l] : 0.f;
        float u21 = xp ? up[(j + 2) * LPAD + l + 1] : 0.f;
        float u22 = (xp && yp) ? up[(j + 2) * LPAD + l + 2] : 0.f;
        float f0 = (u20 + 2.f * u21 + u22) - (u00 + 2.f * u01 + u02);
        float f1 = (u02 + 2.f * u12 + u22) - (u00 + 2.f * u10 + u20);
        float av = Aplan[c * XY + wb];
        float ah = av * 0.5f;
        float al = fminf(ah * ah, 1.0f);
        f0 = fminf(fmaxf(f0 * (1.f - al) - cg0 * al, -MA), MA);
        f1 = fminf(fmaxf(f1 * (1.f - al) - cg1 * al, -MA), MA);
        Ft[(0 * 3 + c) * FROW * LPAD + j * LPAD + l] = f0;
        Ft[(1 * 3 + c) * FROW * LPAD + j * LPAD + l] = f1;
        At[c * FROW * LPAD + j * LPAD + l] = av;
      }
    }
    __syncthreads();

    // D3: per-cell 5x5 gather. Exact skip: |DT*F| <= 0.87, box halfwidth
    // 1.15 -> |shift|>=3 has area==0 -> e==0 contributes nothing.
    const int tr = tid >> 5, tcol = tid & 31;
    const int tx = x0 + tr, ty = y0 + tcol;
    const float SIGMA = 0.65f;
    const float INV4S2 = 1.0f / (4.0f * 0.65f * 0.65f);
    const float DT = 0.2f;
    const float px = tx + 0.5f;
    const float py = ty + 0.5f;
    float accA[3] = {0.f, 0.f, 0.f};
    float accP[NK];
#pragma unroll
    for (int k = 0; k < NK; ++k) accP[k] = 0.f;
    float esum = 0.f;
    for (int dx = -2; dx <= 2; ++dx) {
      for (int dy = -2; dy <= 2; ++dy) {
        const int j = tr - dx + 2;     // 0..11
        const int l = tcol - dy + 2;   // 0..35
        const int sx = (tx - dx) & 255;
        const int sy = (ty - dy) & 255;
        const float spx = sx + 0.5f;
        const float spy = sy + 0.5f;
        float sumnA = 0.f;
        float nAc[3];
#pragma unroll
        for (int c = 0; c < NC; ++c) {
          float f0 = Ft[(0 * 3 + c) * FROW * LPAD + j * LPAD + l];
          float f1 = Ft[(1 * 3 + c) * FROW * LPAD + j * LPAD + l];
          float mu0 = fminf(fmaxf(spx + DT * f0, SIGMA), 256.f - SIGMA);
          float mu1 = fminf(fmaxf(spy + DT * f1, SIGMA), 256.f - SIGMA);
          float sz0 = 0.5f - fabsf(px - mu0) + SIGMA;
          float sz1 = 0.5f - fabsf(py - mu1) + SIGMA;
          sz0 = fminf(fmaxf(sz0, 0.f), 1.f);
          sz1 = fminf(fmaxf(sz1, 0.f), 1.f);
          float area = sz0 * sz1 * INV4S2;
          float na = At[c * FROW * LPAD + j * LPAD + l] * area;
          nAc[c] = na;
          sumnA += na;
        }
        if (__any(sumnA != 0.f)) {
          float e = __expf(sumnA) - 1.0f;
          accA[0] += nAc[0];
          accA[1] += nAc[1];
          accA[2] += nAc[2];
          esum += e;
          const int sb = sx * 256 + sy;
#pragma unroll
          for (int k = 0; k < NK; ++k) accP[k] += Pplan[k * XY + sb] * e;
        }
      }
    }
    const float inv = 1.0f / (esum + 1e-10f);

    // D4: stage outputs (aliased LDS) -> coalesced interleaved writes.
    __syncthreads();
#pragma unroll
    for (int c = 0; c < NC; ++c) AoutS[tr * 96 + tcol * 3 + c] = accA[c];
#pragma unroll
    for (int k = 0; k < NK; ++k) PoutS[tr * 480 + tcol * 15 + k] = accP[k] * inv;
    __syncthreads();
    for (int i = tid; i < 8 * 96; i += 256) {
      const int row = i / 96, off = i - row * 96;
      outA[((x0 + row) * 256 + y0) * 3 + off] = AoutS[i];
    }
    for (int i = tid; i < 8 * 480; i += 256) {
      const int row = i / 480, off = i - row * 480;
      outP[((x0 + row) * 256 + y0) * NK + off] = PoutS[i];
    }
  }
}

extern "C" void kernel_launch(void* const* d_in, const int* in_sizes, int n_in,
                              void* d_out, int out_size, void* d_ws, size_t ws_size,
                              hipStream_t stream) {
  const float* A   = (const float*)d_in[0];
  const float* P   = (const float*)d_in[1];
  const float* fKr = (const float*)d_in[2];
  const float* fKi = (const float*)d_in[3];
  const float* m   = (const float*)d_in[4];
  const float* s   = (const float*)d_in[5];

  float* ws = (float*)d_ws;
  float2* RF    = (float2*)ws;             // 3*XY complex
  float2* T2    = RF + NC * XY;            // 15*XY complex
  float*  G     = (float*)(T2 + NK * XY);  // 15*XY
  float*  Aplan = G + NK * XY;             // 3*XY
  float*  Asum  = Aplan + NC * XY;         // XY
  float*  Pplan = Asum + XY;               // 15*XY

  float* outA = (float*)d_out;
  float* outP = outA + NC * XY;

  void* args[] = {(void*)&A, (void*)&P, (void*)&fKr, (void*)&fKi,
                  (void*)&m, (void*)&s, (void*)&RF, (void*)&T2,
                  (void*)&G, (void*)&Aplan, (void*)&Asum, (void*)&Pplan,
                  (void*)&outA, (void*)&outP};
  hipLaunchCooperativeKernel((void*)k_fused, dim3(512), dim3(256), args, 0,
                             stream);
}

// Round 8
// 111.791 us; speedup vs baseline: 2.9236x; 2.9236x over previous
//
#include <hip/hip_runtime.h>

// FlowLenia step, SX=SY=256, C=3, K=15. 4 dispatches (the dependency minimum:
// 3 transpose syncs + 1 halo sync), composed from previously-validated parts.
//   KA: prep (de-interleave P,A) | row-FFT of A            -> Pplan,Aplan,Asum,RF
//   KB: fwd col-FFT + fK mul + inv col-FFT per k           -> T2  (round-3 K2)
//   KC: inv row-FFT + growth*Pplan + 5-k collapse          -> Ucol (round-5 K3)
//   KD: fused Sobel flow + 5x5 reintegration + softmax mix -> d_out (round-5 K45)

#define XY  65536
#define NC  3
#define NK  15
#define WPAD 260   // per-wave LDS FFT buffer stride (float2)

__device__ __forceinline__ float2 cmul(float2 a, float2 b) {
  return make_float2(a.x * b.x - a.y * b.y, a.x * b.y + a.y * b.x);
}

// 256-pt Stockham radix-4 FFT on a wave-private 256-float2 LDS buffer pair.
// t = lane (0..63). sign = -1 fwd, +1 inv (unnormalized). Result lands in b0.
// All waves of the block must call together (uniform control flow per block).
__device__ __forceinline__ void fft256_lds(float2* b0, float2* b1, int t, float sign) {
  float2* src = b0;
  float2* dst = b1;
#pragma unroll
  for (int stage = 0; stage < 4; ++stage) {
    __syncthreads();  // covers caller's fill and previous stage's writes
    const int Ns = 1 << (2 * stage);
    float2 v0 = src[t];
    float2 v1 = src[t + 64];
    float2 v2 = src[t + 128];
    float2 v3 = src[t + 192];
    const int jm = t & (Ns - 1);
    float ang = sign * 6.283185307179586f * (float)jm / (float)(Ns * 4);
    float sn, cs;
    __sincosf(ang, &sn, &cs);
    float2 w1 = make_float2(cs, sn);
    float2 w2 = cmul(w1, w1);
    float2 w3 = cmul(w2, w1);
    v1 = cmul(v1, w1);
    v2 = cmul(v2, w2);
    v3 = cmul(v3, w3);
    float2 a0 = make_float2(v0.x + v2.x, v0.y + v2.y);
    float2 a1 = make_float2(v0.x - v2.x, v0.y - v2.y);
    float2 a2 = make_float2(v1.x + v3.x, v1.y + v3.y);
    float2 a3 = make_float2(v1.x - v3.x, v1.y - v3.y);
    float2 ia3 = make_float2(-sign * a3.y, sign * a3.x);  // (sign*i)*a3
    const int idxD = ((t >> (2 * stage)) << (2 * stage)) * 4 + jm;  // (t/Ns)*4Ns+jm
    dst[idxD]          = make_float2(a0.x + a2.x, a0.y + a2.y);
    dst[idxD + Ns]     = make_float2(a1.x + ia3.x, a1.y + ia3.y);
    dst[idxD + 2 * Ns] = make_float2(a0.x - a2.x, a0.y - a2.y);
    dst[idxD + 3 * Ns] = make_float2(a1.x - ia3.x, a1.y - ia3.y);
    float2* tmp = src; src = dst; dst = tmp;
  }
  __syncthreads();
}

// KA: blocks 0..191: row-FFT of A (768 wave-tasks, 4/block); blocks 192..447:
// de-interleave P/A + Asum. grid = 448 x 256.
__global__ __launch_bounds__(256) void k_prep_rowfft(const float* __restrict__ A,
                                                     const float* __restrict__ P,
                                                     float2* __restrict__ RF,
                                                     float* __restrict__ Aplan,
                                                     float* __restrict__ Asum,
                                                     float* __restrict__ Pplan) {
  const int tid = threadIdx.x;
  const int bid = blockIdx.x;
  if (bid < 192) {
    __shared__ float2 fbuf[8 * WPAD];
    const int w = tid >> 6, lane = tid & 63;
    const int g = bid * 4 + w;        // 768 tasks (c,x)
    const int c = g >> 8, x = g & 255;
    float2* b0 = fbuf + w * WPAD;
    float2* b1 = fbuf + (4 + w) * WPAD;
#pragma unroll
    for (int r = 0; r < 4; ++r) {
      int y = lane + 64 * r;
      b0[y] = make_float2(A[(x * 256 + y) * NC + c], 0.0f);
    }
    fft256_lds(b0, b1, lane, -1.0f);
#pragma unroll
    for (int r = 0; r < 4; ++r) {
      int y = lane + 64 * r;
      RF[(c * 256 + x) * 256 + y] = b0[y];
    }
  } else {
    const int b = (bid - 192) * 256 + tid;   // 65536 cells
    float a0 = A[b * 3 + 0], a1 = A[b * 3 + 1], a2 = A[b * 3 + 2];
    Aplan[0 * XY + b] = a0;
    Aplan[1 * XY + b] = a1;
    Aplan[2 * XY + b] = a2;
    Asum[b] = a0 + a1 + a2;
#pragma unroll
    for (int k = 0; k < NK; ++k) Pplan[k * XY + b] = P[b * NK + k];
  }
}

// KB: per (k, 8-column tile): fwd col FFT (redundant across a channel's 5 k's
// -- compute is free), fK multiply, inverse col FFT. grid = 15*32 x 512.
__global__ __launch_bounds__(512, 1) void k_colfft(const float* __restrict__ fKr,
                                                   const float* __restrict__ fKi,
                                                   const float2* __restrict__ RF,
                                                   float2* __restrict__ T2) {
  __shared__ float2 lds0[8 * WPAD];
  __shared__ float2 lds1[8 * WPAD];
  const int tid = threadIdx.x;
  const int k = blockIdx.x >> 5;
  const int y0 = (blockIdx.x & 31) << 3;
  const int c = k % 3;

  // Tile load: chunk q (16B) of row x holds columns y0+2q, y0+2q+1.
  {
    const int q = tid & 3;
#pragma unroll
    for (int r = 0; r < 2; ++r) {
      const int x = (tid >> 2) + (r << 7);
      const float4* src = (const float4*)(RF + (c * XY + x * 256 + y0));
      float4 v = src[q];
      lds0[(2 * q) * WPAD + x]     = make_float2(v.x, v.y);
      lds0[(2 * q + 1) * WPAD + x] = make_float2(v.z, v.w);
    }
  }

  const int w = tid >> 6, lane = tid & 63;
  float2* b0 = lds0 + w * WPAD;
  float2* b1 = lds1 + w * WPAD;
  fft256_lds(b0, b1, lane, -1.0f);  // leading barrier covers tile fill

  const int y = y0 + w;
  float2 fa[4];
#pragma unroll
  for (int r = 0; r < 4; ++r) fa[r] = b0[lane + 64 * r];
#pragma unroll
  for (int r = 0; r < 4; ++r) {
    const int x = lane + 64 * r;
    const int fi = (x * 256 + y) * NK + k;
    float2 Kv = make_float2(fKr[fi], fKi[fi]);
    b0[x] = cmul(Kv, fa[r]);
  }
  fft256_lds(b0, b1, lane, 1.0f);   // trailing barrier: tile block-visible

  // Tile store: mirror of the load.
  {
    const int q = tid & 3;
#pragma unroll
    for (int r = 0; r < 2; ++r) {
      const int x = (tid >> 2) + (r << 7);
      float2 v0 = lds0[(2 * q) * WPAD + x];
      float2 v1 = lds0[(2 * q + 1) * WPAD + x];
      float4* dst = (float4*)(T2 + (k * XY + x * 256 + y0));
      dst[q] = make_float4(v0.x, v0.y, v1.x, v1.y);
    }
  }
}

// KC: per (c, x): 5 waves, wave j handles k=c+3j: inverse row FFT, growth*P,
// cross-wave collapse -> Ucol channel. grid = 3*256 x 320.
__global__ __launch_bounds__(320, 1) void k_irowfft_growth(const float2* __restrict__ T2,
                                                           const float* __restrict__ Pplan,
                                                           const float* __restrict__ m,
                                                           const float* __restrict__ s,
                                                           float* __restrict__ Ucol) {
  __shared__ float2 lds0[5 * WPAD];
  __shared__ float2 lds1[5 * WPAD];
  __shared__ float accs[5 * WPAD];
  const int tid = threadIdx.x;
  const int x = blockIdx.x & 255;
  const int c = blockIdx.x >> 8;
  const int j = tid >> 6, lane = tid & 63;
  const int k = c + 3 * j;

  float2* b0 = lds0 + j * WPAD;
  float2* b1 = lds1 + j * WPAD;
  const float2* src = T2 + (k * XY + x * 256);
#pragma unroll
  for (int r = 0; r < 4; ++r) {
    int y = lane + 64 * r;
    b0[y] = src[y];
  }
  fft256_lds(b0, b1, lane, 1.0f);

  const float mk = m[k];
  const float sk = s[k];
  const float inv2s2 = 0.5f / (sk * sk);
  const float* pk = Pplan + k * XY + x * 256;
#pragma unroll
  for (int r = 0; r < 4; ++r) {
    int y = lane + 64 * r;
    float U = b0[y].x * (1.0f / 65536.0f);
    float d = U - mk;
    float g = 2.0f * __expf(-d * d * inv2s2) - 1.0f;
    accs[j * WPAD + y] = g * pk[y];
  }
  __syncthreads();
  if (tid < 256) {
    float sum = 0.f;
#pragma unroll
    for (int j2 = 0; j2 < 5; ++j2) sum += accs[j2 * WPAD + tid];
    Ucol[c * XY + x * 256 + tid] = sum;
  }
}

// KD: fused Sobel flow + reintegration (round-5-validated). 8x32 tile/block.
// Exact 5x5: |DT*F| <= 0.87, box halfwidth 1.15 -> |shift|>=3 has area==0.
#define UROW 14
#define UCOLW 38
#define FROW 12
#define FCOLW 36
#define LPAD 40
__global__ __launch_bounds__(256, 2) void k_flow_reint(const float* __restrict__ Aplan,
                                                       const float* __restrict__ Asum,
                                                       const float* __restrict__ Ucol,
                                                       const float* __restrict__ Pplan,
                                                       float* __restrict__ outA,
                                                       float* __restrict__ outP) {
  __shared__ float smem[3 * UROW * LPAD + UROW * LPAD + 6 * FROW * LPAD + 3 * FROW * LPAD];
  float* Uc = smem;                         // [3][14][40]
  float* As = Uc + 3 * UROW * LPAD;         // [14][40]
  float* Ft = As + UROW * LPAD;             // [6][12][40]
  float* At = Ft + 6 * FROW * LPAD;         // [3][12][40]
  float* PoutS = smem;                      // staging aliases (post-barrier)
  float* AoutS = smem + 8 * 480;

  const int tid = threadIdx.x;
  const int x0 = (blockIdx.x >> 3) << 3;    // 32 x-tiles of 8 rows
  const int y0 = (blockIdx.x & 7) << 5;     // 8 y-tiles of 32 cols

  // Phase 1: load Ucol (3 planes) + Asum with halo 3, wrapped.
  for (int i = tid; i < UROW * UCOLW; i += 256) {
    const int lx = i / UCOLW, ly = i - lx * UCOLW;
    const int gx = (x0 - 3 + lx) & 255;
    const int gy = (y0 - 3 + ly) & 255;
    const int g = gx * 256 + gy;
    Uc[0 * UROW * LPAD + lx * LPAD + ly] = Ucol[0 * XY + g];
    Uc[1 * UROW * LPAD + lx * LPAD + ly] = Ucol[1 * XY + g];
    Uc[2 * UROW * LPAD + lx * LPAD + ly] = Ucol[2 * XY + g];
    As[lx * LPAD + ly] = Asum[g];
  }
  __syncthreads();

  // Phase 2: compute F (6 planes) + stage A (3 planes), halo 2.
  const float MA = 4.35f;
  for (int i = tid; i < FROW * FCOLW; i += 256) {
    const int j = i / FCOLW, l = i - j * FCOLW;
    const int wx = (x0 - 2 + j) & 255;
    const int wy = (y0 - 2 + l) & 255;
    const bool xm = (wx != 0), xp = (wx != 255);
    const bool ym = (wy != 0), yp = (wy != 255);
    float a00 = (xm && ym) ? As[(j) * LPAD + l] : 0.f;
    float a01 = xm ? As[(j) * LPAD + l + 1] : 0.f;
    float a02 = (xm && yp) ? As[(j) * LPAD + l + 2] : 0.f;
    float a10 = ym ? As[(j + 1) * LPAD + l] : 0.f;
    float a12 = yp ? As[(j + 1) * LPAD + l + 2] : 0.f;
    float a20 = (xp && ym) ? As[(j + 2) * LPAD + l] : 0.f;
    float a21 = xp ? As[(j + 2) * LPAD + l + 1] : 0.f;
    float a22 = (xp && yp) ? As[(j + 2) * LPAD + l + 2] : 0.f;
    float cg0 = (a20 + 2.f * a21 + a22) - (a00 + 2.f * a01 + a02);
    float cg1 = (a02 + 2.f * a12 + a22) - (a00 + 2.f * a10 + a20);
    const int wb = wx * 256 + wy;
#pragma unroll
    for (int c = 0; c < NC; ++c) {
      const float* up = Uc + c * UROW * LPAD;
      float u00 = (xm && ym) ? up[(j) * LPAD + l] : 0.f;
      float u01 = xm ? up[(j) * LPAD + l + 1] : 0.f;
      float u02 = (xm && yp) ? up[(j) * LPAD + l + 2] : 0.f;
      float u10 = ym ? up[(j + 1) * LPAD + l] : 0.f;
      float u12 = yp ? up[(j + 1) * LPAD + l + 2] : 0.f;
      float u20 = (xp && ym) ? up[(j + 2) * LPAD + l] : 0.f;
      float u21 = xp ? up[(j + 2) * LPAD + l + 1] : 0.f;
      float u22 = (xp && yp) ? up[(j + 2) * LPAD + l + 2] : 0.f;
      float f0 = (u20 + 2.f * u21 + u22) - (u00 + 2.f * u01 + u02);
      float f1 = (u02 + 2.f * u12 + u22) - (u00 + 2.f * u10 + u20);
      float av = Aplan[c * XY + wb];
      float ah = av * 0.5f;
      float al = fminf(ah * ah, 1.0f);
      f0 = fminf(fmaxf(f0 * (1.f - al) - cg0 * al, -MA), MA);
      f1 = fminf(fmaxf(f1 * (1.f - al) - cg1 * al, -MA), MA);
      Ft[(0 * 3 + c) * FROW * LPAD + j * LPAD + l] = f0;
      Ft[(1 * 3 + c) * FROW * LPAD + j * LPAD + l] = f1;
      At[c * FROW * LPAD + j * LPAD + l] = av;
    }
  }
  __syncthreads();

  // Phase 3: per-cell 5x5 gather (F/A from LDS, P from global, e==0 skip).
  const int tr = tid >> 5, tcol = tid & 31;
  const int tx = x0 + tr, ty = y0 + tcol;
  const float SIGMA = 0.65f;
  const float INV4S2 = 1.0f / (4.0f * 0.65f * 0.65f);
  const float DT = 0.2f;
  const float px = tx + 0.5f;
  const float py = ty + 0.5f;
  float accA[3] = {0.f, 0.f, 0.f};
  float accP[NK];
#pragma unroll
  for (int k = 0; k < NK; ++k) accP[k] = 0.f;
  float esum = 0.f;
  for (int dx = -2; dx <= 2; ++dx) {
    for (int dy = -2; dy <= 2; ++dy) {
      const int j = tr - dx + 2;     // 0..11
      const int l = tcol - dy + 2;   // 0..35
      const int sx = (tx - dx) & 255;
      const int sy = (ty - dy) & 255;
      const float spx = sx + 0.5f;
      const float spy = sy + 0.5f;
      float sumnA = 0.f;
      float nAc[3];
#pragma unroll
      for (int c = 0; c < NC; ++c) {
        float f0 = Ft[(0 * 3 + c) * FROW * LPAD + j * LPAD + l];
        float f1 = Ft[(1 * 3 + c) * FROW * LPAD + j * LPAD + l];
        float mu0 = fminf(fmaxf(spx + DT * f0, SIGMA), 256.f - SIGMA);
        float mu1 = fminf(fmaxf(spy + DT * f1, SIGMA), 256.f - SIGMA);
        float sz0 = 0.5f - fabsf(px - mu0) + SIGMA;
        float sz1 = 0.5f - fabsf(py - mu1) + SIGMA;
        sz0 = fminf(fmaxf(sz0, 0.f), 1.f);
        sz1 = fminf(fmaxf(sz1, 0.f), 1.f);
        float area = sz0 * sz1 * INV4S2;
        float na = At[c * FROW * LPAD + j * LPAD + l] * area;
        nAc[c] = na;
        sumnA += na;
      }
      if (__any(sumnA != 0.f)) {
        float e = __expf(sumnA) - 1.0f;
        accA[0] += nAc[0];
        accA[1] += nAc[1];
        accA[2] += nAc[2];
        esum += e;
        const int sb = sx * 256 + sy;
#pragma unroll
        for (int k = 0; k < NK; ++k) accP[k] += Pplan[k * XY + sb] * e;
      }
    }
  }
  const float inv = 1.0f / (esum + 1e-10f);

  // Phase 4: stage outputs (aliased LDS) -> coalesced interleaved writes.
  __syncthreads();
#pragma unroll
  for (int c = 0; c < NC; ++c) AoutS[tr * 96 + tcol * 3 + c] = accA[c];
#pragma unroll
  for (int k = 0; k < NK; ++k) PoutS[tr * 480 + tcol * 15 + k] = accP[k] * inv;
  __syncthreads();
  for (int i = tid; i < 8 * 96; i += 256) {
    const int row = i / 96, off = i - row * 96;
    outA[((x0 + row) * 256 + y0) * 3 + off] = AoutS[i];
  }
  for (int i = tid; i < 8 * 480; i += 256) {
    const int row = i / 480, off = i - row * 480;
    outP[((x0 + row) * 256 + y0) * NK + off] = PoutS[i];
  }
}

extern "C" void kernel_launch(void* const* d_in, const int* in_sizes, int n_in,
                              void* d_out, int out_size, void* d_ws, size_t ws_size,
                              hipStream_t stream) {
  const float* A   = (const float*)d_in[0];
  const float* P   = (const float*)d_in[1];
  const float* fKr = (const float*)d_in[2];
  const float* fKi = (const float*)d_in[3];
  const float* m   = (const float*)d_in[4];
  const float* s   = (const float*)d_in[5];

  float* ws = (float*)d_ws;
  float2* RF    = (float2*)ws;             // 3*XY complex
  float2* T2    = RF + NC * XY;            // 15*XY complex
  float*  Ucol  = (float*)(T2 + NK * XY);  // 3*XY
  float*  Aplan = Ucol + NC * XY;          // 3*XY
  float*  Asum  = Aplan + NC * XY;         // XY
  float*  Pplan = Asum + XY;               // 15*XY

  float* outA = (float*)d_out;
  float* outP = outA + NC * XY;

  k_prep_rowfft<<<448, 256, 0, stream>>>(A, P, RF, Aplan, Asum, Pplan);
  k_colfft<<<NK * 32, 512, 0, stream>>>(fKr, fKi, RF, T2);
  k_irowfft_growth<<<NC * 256, 320, 0, stream>>>(T2, Pplan, m, s, Ucol);
  k_flow_reint<<<256, 256, 0, stream>>>(Aplan, Asum, Ucol, Pplan, outA, outP);
}